// Round 3
// baseline (2026.342 us; speedup 1.0000x reference)
//
#include <hip/hip_runtime.h>
#include <hip/hip_bf16.h>
#include <math.h>

typedef __hip_bfloat16 bf16;
using f32x4  = __attribute__((ext_vector_type(4))) float;
using bf16x8 = __attribute__((ext_vector_type(8))) short;

static __device__ __forceinline__ float b2f(bf16 v) { return __bfloat162float(v); }
static __device__ __forceinline__ short f2b_s(float f) {
    bf16 b = __float2bfloat16(f);
    return *reinterpret_cast<short*>(&b);
}

// ---------------- fp32 -> bf16 weight conversion ----------------
__global__ __launch_bounds__(256) void f2b_kernel(const float* __restrict__ in,
                                                  short* __restrict__ out, int n4)
{
    int i = blockIdx.x * 256 + threadIdx.x;
    if (i < n4) {
        float4 f = reinterpret_cast<const float4*>(in)[i];
        short4 s;
        s.x = f2b_s(f.x); s.y = f2b_s(f.y); s.z = f2b_s(f.z); s.w = f2b_s(f.w);
        reinterpret_cast<short4*>(out)[i] = s;
    }
}

// ---------------- LayerNorm (+ optional window partition), f32 in -> bf16 out --
__global__ __launch_bounds__(64) void ln_kernel(
    const float* __restrict__ in, const float* __restrict__ g,
    const float* __restrict__ bta, bf16* __restrict__ out, int windowed)
{
    int lr  = blockIdx.x;
    int tid = threadIdx.x;
    const float* xr = in + (size_t)lr * 512;
    int c0 = tid * 8;
    float4 f0 = *reinterpret_cast<const float4*>(xr + c0);
    float4 f1 = *reinterpret_cast<const float4*>(xr + c0 + 4);
    float v[8] = { f0.x, f0.y, f0.z, f0.w, f1.x, f1.y, f1.z, f1.w };
    float s = 0.f, s2 = 0.f;
#pragma unroll
    for (int k = 0; k < 8; ++k) { s += v[k]; s2 += v[k] * v[k]; }
#pragma unroll
    for (int off = 32; off; off >>= 1) {
        s  += __shfl_xor(s,  off, 64);
        s2 += __shfl_xor(s2, off, 64);
    }
    float mean = s * (1.0f / 512.0f);
    float var  = s2 * (1.0f / 512.0f) - mean * mean;
    float inv  = rsqrtf(var + 1e-5f);
    size_t drow;
    if (windowed) {
        int b_loc = lr >> 12;
        int l  = lr & 4095;
        int gr = l >> 6, gc = l & 63;
        int wy = gr >> 3, iy = gr & 7, wx = gc >> 3, ix = gc & 7;
        drow = (size_t)((b_loc * 64 + wy * 8 + wx) * 64 + iy * 8 + ix);
    } else {
        drow = (size_t)lr;
    }
    bf16* orow = out + drow * 512;
#pragma unroll
    for (int k = 0; k < 8; ++k) {
        int c = c0 + k;
        orow[c] = __float2bfloat16((v[k] - mean) * inv * g[c] + bta[c]);
    }
}

// ---------------- MFMA GEMM: C[M,N] = A[M,K](bf16) @ W[N,K]^T(bf16) ------------
// LDS-FREE, BARRIER-FREE: each wave owns a 64x64 output tile (4x4 frags of
// mfma_f32_16x16x32_bf16) and loads A/B fragments DIRECTLY from global into
// registers. A wave's fragment load covers 16 rows x 64B = 16 full cache lines
// (perfectly line-coalesced); weights are L2-resident; XCD swizzle keeps the
// A row-panel L2-hot across its column-block neighbors. No __syncthreads =>
// no vmcnt(0) drain; compiler pipelines register loads with counted vmcnt.
// modes: 0 = +bias -> bf16 dst
//        1 = +bias + residual(res f32, window-reversed LOCAL idx) -> f32 dst
//        2 = +bias, exact GELU -> bf16 dst
//        3 = +bias + residual(res f32, same local idx) -> f32 dst (final output)
__global__ __launch_bounds__(256) void gemm_mfma(
    const bf16* __restrict__ A, const short* __restrict__ W,
    const float* __restrict__ bias, int N, int K, int mode,
    void* __restrict__ dstv, const float* __restrict__ res)
{
    int tid  = threadIdx.x;
    int wave = tid >> 6, lane = tid & 63;
    int waveM = wave >> 1, waveN = wave & 1;

    // T1: XCD-aware bijective swizzle; each XCD owns a contiguous chunk of
    // linear block ids, x (column blocks) walking fastest -> A-panel L2 reuse.
    int nx  = gridDim.x;
    int nwg = nx * gridDim.y;
    int lid = blockIdx.y * nx + blockIdx.x;
    int nid = lid;
    if ((nwg & 7) == 0) nid = (lid & 7) * (nwg >> 3) + (lid >> 3);
    int mBase = (nid / nx) * 128;
    int nBase = (nid % nx) * 128;

    int l15 = lane & 15;
    int kq  = (lane >> 4) * 8;                   // quad k-offset (elements)

    // fragment base pointers: lane l reads row (base + l15), cols kb+kq..kq+8
    const bf16*  A0 = A + (size_t)(mBase + waveM * 64 + l15) * K + kq;
    const short* B0 = W + (size_t)(nBase + waveN * 64 + l15) * K + kq;
    size_t rs = (size_t)16 * K;                  // 16-row stride

    f32x4 acc[4][4] = {};

#pragma unroll 2
    for (int kb = 0; kb < K; kb += 32) {
        bf16x8 af[4], bfv[4];
#pragma unroll
        for (int i = 0; i < 4; ++i)
            af[i] = *reinterpret_cast<const bf16x8*>(A0 + rs * i + kb);
#pragma unroll
        for (int j = 0; j < 4; ++j)
            bfv[j] = *reinterpret_cast<const bf16x8*>(B0 + rs * j + kb);
#pragma unroll
        for (int i = 0; i < 4; ++i)
#pragma unroll
            for (int j = 0; j < 4; ++j)
                acc[i][j] = __builtin_amdgcn_mfma_f32_16x16x32_bf16(af[i], bfv[j], acc[i][j], 0, 0, 0);
    }

    // epilogue: C/D layout col=lane&15, row=(lane>>4)*4+reg
    int rq = (lane >> 4) * 4;
#pragma unroll
    for (int j = 0; j < 4; ++j) {
        int n = nBase + waveN * 64 + j * 16 + l15;
        float bn = bias[n];
#pragma unroll
        for (int i = 0; i < 4; ++i) {
#pragma unroll
            for (int reg = 0; reg < 4; ++reg) {
                int m = mBase + waveM * 64 + i * 16 + rq + reg;
                float v = acc[i][j][reg] + bn;
                if (mode == 0) {
                    ((bf16*)dstv)[(size_t)m * N + n] = __float2bfloat16(v);
                } else if (mode == 1) {
                    int b_loc = m >> 12, w = (m >> 6) & 63, tk = m & 63;
                    int wy = w >> 3, wx = w & 7, iy = tk >> 3, ix = tk & 7;
                    int l = ((wy << 3) + iy) * 64 + (wx << 3) + ix;
                    size_t idx = ((size_t)(b_loc * 4096 + l)) * 512 + n;
                    ((float*)dstv)[idx] = v + res[idx];
                } else if (mode == 2) {
                    float gl = 0.5f * v * (1.0f + erff(v * 0.70710678118654752f));
                    ((bf16*)dstv)[(size_t)m * N + n] = __float2bfloat16(gl);
                } else {
                    size_t idx = (size_t)m * N + n;
                    ((float*)dstv)[idx] = v + res[idx];
                }
            }
        }
    }
}

// ---------------- Fused windowed attention, MFMA version ----------------
// One block (256 thr = 4 waves) per window; 16 heads looped inside.
__global__ __launch_bounds__(256) void attn_kernel(
    const bf16* __restrict__ qkv, const float* __restrict__ Dofs,
    const float* __restrict__ a_p, const float* __restrict__ b_p,
    const float* __restrict__ a_r, const float* __restrict__ b_r,
    bf16* __restrict__ xattn)
{
    __shared__ float cosr[15][64];    // cos((rad)*D[j]*c_r), index k=rad+7
    __shared__ float sinr[15][64];
    __shared__ float aphiS[15][16];   // A_phi(az,h), index az+7
    __shared__ float arsS[15][16];    // a_r[(rad)%15][h], index rad+7
    __shared__ float brsS[15][16];
    __shared__ short Vt[32][72];      // V^T per head: Vt[d][j]; 144B rows (16B-aligned)
    __shared__ short Psh[64][72];     // P (bf16, unnormalized) per head

    int b_ = blockIdx.x;              // window index within group
    int bl = b_ >> 6;
    int w  = b_ & 63;
    int wy = w >> 3, wx = w & 7;
    int tid  = threadIdx.x;
    int wave = tid >> 6, lane = tid & 63;

    const float scale = 0.17677669529663687f;   // 1/sqrt(32)
    const float c_az  = 0.09817477042468103f;   // 2*pi/64
    const float c_r   = 0.02454369260617026f;   // 2*pi/256

    // ---- per-window tables (head-independent trig: computed ONCE, not 16x) ----
    for (int t = tid; t < 960; t += 256) {
        int k = t >> 6;               // rad+7 in [0,15)
        int j = t & 63;
        int jy = j >> 3, jx = j & 7;
        float Dj  = Dofs[(size_t)bl * 4096 + (wy * 8 + jy) * 64 + (wx * 8 + jx)];
        float ang = (float)(k - 7) * Dj * c_r;
        cosr[k][j] = __cosf(ang);
        sinr[k][j] = __sinf(ang);
    }
    if (tid < 240) {
        int k = tid >> 4;             // offset+7 in [0,15)
        int h = tid & 15;
        int v = k - 7;
        int ip = v < 0 ? v + 15 : v;  // torch negative-index == mod
        float azf = (float)v * c_az;
        aphiS[k][h] = a_p[ip * 16 + h] * __cosf(azf) + b_p[ip * 16 + h] * __sinf(azf);
        arsS[k][h]  = a_r[ip * 16 + h];
        brsS[k][h]  = b_r[ip * 16 + h];
    }

    int i_blk = wave;                 // this wave's 16 query rows
    int l15 = lane & 15;
    int lq  = lane >> 4;              // 0..3
    int m0  = i_blk * 16 + lq * 4;    // row of reg 0 (D-layout)
    const bf16* qbase = qkv + (size_t)(b_ * 64) * 1536;
    bf16* obase = xattn + (size_t)(b_ * 64) * 512;

    for (int h = 0; h < 16; ++h) {
        __syncthreads();              // prev head's PV done (and tables ready at h=0)
        // ---- stage V^T for this head: thread t -> token t>>2, dims (t&3)*8..+8 ----
        {
            int tok = tid >> 2, dc = (tid & 3) * 8;
            bf16x8 vv = *reinterpret_cast<const bf16x8*>(
                qkv + (size_t)(b_ * 64 + tok) * 1536 + 1024 + h * 32 + dc);
#pragma unroll
            for (int s = 0; s < 8; ++s) Vt[dc + s][tok] = vv[s];
        }
        __syncthreads();              // Vt ready for all waves

        // ---- QK^T: 4 MFMAs (K=32 in one shot), frags straight from global ----
        bf16x8 af = *reinterpret_cast<const bf16x8*>(
            qbase + (size_t)(i_blk * 16 + l15) * 1536 + h * 32 + lq * 8);
        f32x4 Sacc[4] = {};
#pragma unroll
        for (int jb = 0; jb < 4; ++jb) {
            bf16x8 kf = *reinterpret_cast<const bf16x8*>(
                qbase + (size_t)(jb * 16 + l15) * 1536 + 512 + h * 32 + lq * 8);
            Sacc[jb] = __builtin_amdgcn_mfma_f32_16x16x32_bf16(af, kf, Sacc[jb], 0, 0, 0);
        }

        // ---- bias + row softmax in registers ----
        float Sv[4][4];               // [reg][jb]
        float inv[4];
#pragma unroll
        for (int reg = 0; reg < 4; ++reg) {
            int m = m0 + reg;
            int iy = m >> 3, ix = m & 7;
            float rmax = -1e30f;
#pragma unroll
            for (int jb = 0; jb < 4; ++jb) {
                int n = jb * 16 + l15;
                int jy = n >> 3, jx = n & 7;
                int ai = ix - jx + 7;
                int ri = iy - jy + 7;
                float sc = Sacc[jb][reg] * scale + aphiS[ai][h]
                         + arsS[ri][h] * cosr[ri][n] + brsS[ri][h] * sinr[ri][n];
                Sv[reg][jb] = sc;
                rmax = fmaxf(rmax, sc);
            }
#pragma unroll
            for (int off = 1; off <= 8; off <<= 1)
                rmax = fmaxf(rmax, __shfl_xor(rmax, off, 64));
            float rsum = 0.f;
#pragma unroll
            for (int jb = 0; jb < 4; ++jb) {
                float e = __expf(Sv[reg][jb] - rmax);
                Sv[reg][jb] = e;
                rsum += e;
            }
#pragma unroll
            for (int off = 1; off <= 8; off <<= 1)
                rsum += __shfl_xor(rsum, off, 64);
            inv[reg] = 1.0f / rsum;
        }

        // ---- P (bf16, unnormalized) -> LDS; own rows only, no barrier needed ----
#pragma unroll
        for (int reg = 0; reg < 4; ++reg)
#pragma unroll
            for (int jb = 0; jb < 4; ++jb)
                Psh[m0 + reg][jb * 16 + l15] = f2b_s(Sv[reg][jb]);

        // ---- PV: out[m][d] = sum_j P[m][j] * Vt[d][j]; 4 MFMAs ----
        f32x4 o[2] = {};
#pragma unroll
        for (int ks = 0; ks < 2; ++ks) {
            bf16x8 pa = *reinterpret_cast<const bf16x8*>(
                &Psh[i_blk * 16 + l15][ks * 32 + lq * 8]);
#pragma unroll
            for (int nb = 0; nb < 2; ++nb) {
                bf16x8 bv = *reinterpret_cast<const bf16x8*>(
                    &Vt[nb * 16 + l15][ks * 32 + lq * 8]);
                o[nb] = __builtin_amdgcn_mfma_f32_16x16x32_bf16(pa, bv, o[nb], 0, 0, 0);
            }
        }

        // ---- epilogue: normalize by row-sum, store bf16 ----
#pragma unroll
        for (int nb = 0; nb < 2; ++nb) {
            int d = nb * 16 + l15;
#pragma unroll
            for (int reg = 0; reg < 4; ++reg) {
                int m = m0 + reg;
                obase[(size_t)m * 512 + h * 32 + d] = __float2bfloat16(o[nb][reg] * inv[reg]);
            }
        }
    }
}

// ---------------- launch ----------------
extern "C" void kernel_launch(void* const* d_in, const int* in_sizes, int n_in,
                              void* d_out, int out_size, void* d_ws, size_t ws_size,
                              hipStream_t stream)
{
    const float* x      = (const float*)d_in[0];
    const float* D      = (const float*)d_in[1];
    const float* n1g    = (const float*)d_in[2];
    const float* n1b    = (const float*)d_in[3];
    const float* qkv_w  = (const float*)d_in[4];
    const float* qkv_b  = (const float*)d_in[5];
    const float* proj_w = (const float*)d_in[6];
    const float* proj_b = (const float*)d_in[7];
    const float* a_p    = (const float*)d_in[8];
    const float* b_p    = (const float*)d_in[9];
    const float* a_r    = (const float*)d_in[10];
    const float* b_r    = (const float*)d_in[11];
    const float* n2g    = (const float*)d_in[12];
    const float* n2b    = (const float*)d_in[13];
    const float* fc1_w  = (const float*)d_in[14];
    const float* fc1_b  = (const float*)d_in[15];
    const float* fc2_w  = (const float*)d_in[16];
    const float* fc2_b  = (const float*)d_in[17];
    float* out = (float*)d_out;

    // bf16 weights at ws start: 3,145,728 elems = 6,291,456 B
    char* ws = (char*)d_ws;
    short* qkv_wb  = (short*)ws;                 // 1536*512
    short* proj_wb = qkv_wb + 786432;            // 512*512
    short* fc1_wb  = proj_wb + 262144;           // 2048*512
    short* fc2_wb  = fc1_wb + 1048576;           // 512*2048
    char* gws = (char*)(fc2_wb + 1048576);

    // group-local region: 7168 B per row
    int G = 16;
    while (G > 1 && 6291456 + (size_t)G * 4096 * 7168 > ws_size) G >>= 1;
    int NG = 16 / G;
    size_t rowsA = (size_t)G * 4096;

    float* x2   = (float*)gws;                   // rowsA*512 f32
    bf16*  xw   = (bf16*)(gws + rowsA * 2048);   // rowsA*512 bf16 (also xm)
    bf16*  qkvb = xw + rowsA * 512;              // rowsA*1536 bf16
    bf16*  xatt = qkvb + rowsA * 1536;           // rowsA*512 bf16
    bf16*  xm   = xw;
    bf16*  hbuf = qkvb;                          // rowsA*2048 (spans qkv+xatt)

    // convert weights (every call; graph-safe)
    hipLaunchKernelGGL(f2b_kernel, dim3(768),  dim3(256), 0, stream, qkv_w,  qkv_wb,  196608);
    hipLaunchKernelGGL(f2b_kernel, dim3(256),  dim3(256), 0, stream, proj_w, proj_wb,  65536);
    hipLaunchKernelGGL(f2b_kernel, dim3(1024), dim3(256), 0, stream, fc1_w,  fc1_wb,  262144);
    hipLaunchKernelGGL(f2b_kernel, dim3(1024), dim3(256), 0, stream, fc2_w,  fc2_wb,  262144);

    int gy = (int)(rowsA / 128);

    for (int g = 0; g < NG; ++g) {
        size_t r0 = (size_t)g * rowsA;
        // 1. LN1 + window partition -> xw
        hipLaunchKernelGGL(ln_kernel, dim3((int)rowsA), dim3(64), 0, stream,
                           x + r0 * 512, n1g, n1b, xw, 1);
        // 2. QKV GEMM -> qkvb   [rowsA x 1536, K=512]
        hipLaunchKernelGGL(gemm_mfma, dim3(1536 / 128, gy), dim3(256), 0, stream,
                           xw, qkv_wb, qkv_b, 1536, 512, 0, (void*)qkvb, (const float*)nullptr);
        // 3. fused windowed attention (MFMA, one block per window) -> xatt
        hipLaunchKernelGGL(attn_kernel, dim3(G * 64), dim3(256), 0, stream,
                           qkvb, D + r0, a_p, b_p, a_r, b_r, xatt);
        // 4. proj GEMM + window-reverse + residual(x) -> x2 (f32)
        hipLaunchKernelGGL(gemm_mfma, dim3(512 / 128, gy), dim3(256), 0, stream,
                           xatt, proj_wb, proj_b, 512, 512, 1, (void*)x2, x + r0 * 512);
        // 5. LN2 -> xm
        hipLaunchKernelGGL(ln_kernel, dim3((int)rowsA), dim3(64), 0, stream,
                           x2, n2g, n2b, xm, 0);
        // 6. fc1 GEMM + exact GELU -> hbuf  [rowsA x 2048, K=512]
        hipLaunchKernelGGL(gemm_mfma, dim3(2048 / 128, gy), dim3(256), 0, stream,
                           xm, fc1_wb, fc1_b, 2048, 512, 2, (void*)hbuf, (const float*)nullptr);
        // 7. fc2 GEMM + residual(x2) -> out (fp32)  [K=2048]
        hipLaunchKernelGGL(gemm_mfma, dim3(512 / 128, gy), dim3(256), 0, stream,
                           hbuf, fc2_wb, fc2_b, 512, 2048, 3, (void*)(out + r0 * 512), x2);
    }
}

// Round 4
// 1417.990 us; speedup vs baseline: 1.4290x; 1.4290x over previous
//
#include <hip/hip_runtime.h>
#include <hip/hip_bf16.h>
#include <math.h>

typedef __hip_bfloat16 bf16;
using f32x4  = __attribute__((ext_vector_type(4))) float;
using bf16x8 = __attribute__((ext_vector_type(8))) short;

static __device__ __forceinline__ float b2f(bf16 v) { return __bfloat162float(v); }
static __device__ __forceinline__ short f2b_s(float f) {
    bf16 b = __float2bfloat16(f);
    return *reinterpret_cast<short*>(&b);
}

// async 16B/lane global->LDS; lptr must be the wave-uniform chunk base
static __device__ __forceinline__ void gl_lds16(const void* g, void* l) {
    __builtin_amdgcn_global_load_lds(
        (const __attribute__((address_space(1))) unsigned int*)g,
        (__attribute__((address_space(3))) unsigned int*)l, 16, 0, 0);
}

// ---------------- fp32 -> bf16 weight conversion ----------------
__global__ __launch_bounds__(256) void f2b_kernel(const float* __restrict__ in,
                                                  short* __restrict__ out, int n4)
{
    int i = blockIdx.x * 256 + threadIdx.x;
    if (i < n4) {
        float4 f = reinterpret_cast<const float4*>(in)[i];
        short4 s;
        s.x = f2b_s(f.x); s.y = f2b_s(f.y); s.z = f2b_s(f.z); s.w = f2b_s(f.w);
        reinterpret_cast<short4*>(out)[i] = s;
    }
}

// ---------------- LayerNorm (+ optional window partition), f32 in -> bf16 out --
__global__ __launch_bounds__(64) void ln_kernel(
    const float* __restrict__ in, const float* __restrict__ g,
    const float* __restrict__ bta, bf16* __restrict__ out, int windowed)
{
    int lr  = blockIdx.x;
    int tid = threadIdx.x;
    const float* xr = in + (size_t)lr * 512;
    int c0 = tid * 8;
    float4 f0 = *reinterpret_cast<const float4*>(xr + c0);
    float4 f1 = *reinterpret_cast<const float4*>(xr + c0 + 4);
    float v[8] = { f0.x, f0.y, f0.z, f0.w, f1.x, f1.y, f1.z, f1.w };
    float s = 0.f, s2 = 0.f;
#pragma unroll
    for (int k = 0; k < 8; ++k) { s += v[k]; s2 += v[k] * v[k]; }
#pragma unroll
    for (int off = 32; off; off >>= 1) {
        s  += __shfl_xor(s,  off, 64);
        s2 += __shfl_xor(s2, off, 64);
    }
    float mean = s * (1.0f / 512.0f);
    float var  = s2 * (1.0f / 512.0f) - mean * mean;
    float inv  = rsqrtf(var + 1e-5f);
    size_t drow;
    if (windowed) {
        int b_loc = lr >> 12;
        int l  = lr & 4095;
        int gr = l >> 6, gc = l & 63;
        int wy = gr >> 3, iy = gr & 7, wx = gc >> 3, ix = gc & 7;
        drow = (size_t)((b_loc * 64 + wy * 8 + wx) * 64 + iy * 8 + ix);
    } else {
        drow = (size_t)lr;
    }
    bf16* orow = out + drow * 512;
#pragma unroll
    for (int k = 0; k < 8; ++k) {
        int c = c0 + k;
        orow[c] = __float2bfloat16((v[k] - mean) * inv * g[c] + bta[c]);
    }
}

// ---------------- MFMA GEMM: C[M,N] = A[M,K](bf16) @ W[N,K]^T(bf16) ------------
// 128x128 tile, 4 waves (2x2), each wave 4x4 of mfma_f32_16x16x32_bf16, BK=32.
// T3-minimum double-buffer with STATICALLY-NAMED LDS buffers (As0/As1/Bs0/Bs1,
// no runtime pointer swap -> compiler can disambiguate gl_lds writes to buf(n+1)
// from ds_reads of buf(n), so no conservative vmcnt(0) before the reads).
// Schedule per K-step: STAGE(next) ; ds_read+MFMA(cur) ; asm vmcnt(0) ; s_barrier.
// The stage latency drains UNDER the MFMA cluster, not in front of it.
// T1 XCD-aware bijective block swizzle kept (FETCH 660->~300MB verified R2/R3).
// modes: 0 = +bias -> bf16 dst
//        1 = +bias + residual(res f32, window-reversed LOCAL idx) -> f32 dst
//        2 = +bias, exact GELU -> bf16 dst
//        3 = +bias + residual(res f32, same local idx) -> f32 dst (final output)
__global__ __launch_bounds__(256) void gemm_mfma(
    const bf16* __restrict__ A, const short* __restrict__ W,
    const float* __restrict__ bias, int N, int K, int mode,
    void* __restrict__ dstv, const float* __restrict__ res)
{
    __shared__ short As0[128 * 32];   // row stride 32 elems (64 B); 8 KB each
    __shared__ short Bs0[128 * 32];
    __shared__ short As1[128 * 32];
    __shared__ short Bs1[128 * 32];

    int tid  = threadIdx.x;
    int wave = tid >> 6, lane = tid & 63;
    int waveM = wave >> 1, waveN = wave & 1;

    // T1: XCD-aware bijective swizzle; each XCD owns a contiguous chunk of
    // linear block ids, x (column blocks) walking fastest -> A-panel L2 reuse.
    int nx  = gridDim.x;
    int nwg = nx * gridDim.y;
    int lid = blockIdx.y * nx + blockIdx.x;
    int nid = lid;
    if ((nwg & 7) == 0) nid = (lid & 7) * (nwg >> 3) + (lid >> 3);
    int mBase = (nid / nx) * 128;
    int nBase = (nid % nx) * 128;

    f32x4 acc[4][4] = {};

    // staging: wave w covers rows w*32 .. w*32+31 (two 16-row instructions each)
    int rr   = wave * 32 + (lane >> 2);          // rows w*32 .. w*32+15
    int segE = (lane & 3) * 8;                   // 16B segment within 64B row
    const bf16*  Ag = A + (size_t)(mBase + rr) * K + segE;
    const short* Bg = W + (size_t)(nBase + rr) * K + segE;
    size_t rs16 = (size_t)16 * K;                // 16-row stride in elements

    int mf = waveM * 64 + (lane & 15);           // fragment row (A)
    int nf = waveN * 64 + (lane & 15);           // fragment row (B)
    int kq = (lane >> 4) * 8;                    // quad k-offset

    auto stage = [&](int kb, short* Ad, short* Bd) {
        gl_lds16(Ag + kb,        Ad + wave * 1024);
        gl_lds16(Ag + kb + rs16, Ad + wave * 1024 + 512);
        gl_lds16(Bg + kb,        Bd + wave * 1024);
        gl_lds16(Bg + kb + rs16, Bd + wave * 1024 + 512);
    };
    auto compute = [&](const short* As_, const short* Bs_) {
        bf16x8 af[4], bfv[4];
#pragma unroll
        for (int i = 0; i < 4; ++i)
            af[i] = *reinterpret_cast<const bf16x8*>(&As_[(mf + i * 16) * 32 + kq]);
#pragma unroll
        for (int j = 0; j < 4; ++j)
            bfv[j] = *reinterpret_cast<const bf16x8*>(&Bs_[(nf + j * 16) * 32 + kq]);
#pragma unroll
        for (int i = 0; i < 4; ++i)
#pragma unroll
            for (int j = 0; j < 4; ++j)
                acc[i][j] = __builtin_amdgcn_mfma_f32_16x16x32_bf16(af[i], bfv[j], acc[i][j], 0, 0, 0);
    };

    // ---- prologue: stage K-step 0 into buf 0 ----
    stage(0, As0, Bs0);
    asm volatile("s_waitcnt vmcnt(0)" ::: "memory");
    __builtin_amdgcn_s_barrier();

    int nsteps = K >> 5;                         // always even (K=512 or 2048)
    for (int t = 0; t < nsteps; t += 2) {
        // even half: prefetch (t+1) into buf1, compute (t) from buf0
        stage((t + 1) << 5, As1, Bs1);           // t+1 < nsteps always holds
        compute(As0, Bs0);
        asm volatile("s_waitcnt vmcnt(0)" ::: "memory");
        __builtin_amdgcn_s_barrier();
        // odd half: prefetch (t+2) into buf0, compute (t+1) from buf1
        if (t + 2 < nsteps) stage((t + 2) << 5, As0, Bs0);
        compute(As1, Bs1);
        asm volatile("s_waitcnt vmcnt(0)" ::: "memory");
        __builtin_amdgcn_s_barrier();
    }

    // epilogue: C/D layout col=lane&15, row=(lane>>4)*4+reg
    int rq = (lane >> 4) * 4;
#pragma unroll
    for (int j = 0; j < 4; ++j) {
        int n = nBase + waveN * 64 + j * 16 + (lane & 15);
        float bn = bias[n];
#pragma unroll
        for (int i = 0; i < 4; ++i) {
#pragma unroll
            for (int reg = 0; reg < 4; ++reg) {
                int m = mBase + waveM * 64 + i * 16 + rq + reg;
                float v = acc[i][j][reg] + bn;
                if (mode == 0) {
                    ((bf16*)dstv)[(size_t)m * N + n] = __float2bfloat16(v);
                } else if (mode == 1) {
                    int b_loc = m >> 12, w = (m >> 6) & 63, tk = m & 63;
                    int wy = w >> 3, wx = w & 7, iy = tk >> 3, ix = tk & 7;
                    int l = ((wy << 3) + iy) * 64 + (wx << 3) + ix;
                    size_t idx = ((size_t)(b_loc * 4096 + l)) * 512 + n;
                    ((float*)dstv)[idx] = v + res[idx];
                } else if (mode == 2) {
                    float gl = 0.5f * v * (1.0f + erff(v * 0.70710678118654752f));
                    ((bf16*)dstv)[(size_t)m * N + n] = __float2bfloat16(gl);
                } else {
                    size_t idx = (size_t)m * N + n;
                    ((float*)dstv)[idx] = v + res[idx];
                }
            }
        }
    }
}

// ---------------- Fused windowed attention, MFMA version ----------------
// One block (256 thr = 4 waves) per window; 16 heads looped inside.
__global__ __launch_bounds__(256) void attn_kernel(
    const bf16* __restrict__ qkv, const float* __restrict__ Dofs,
    const float* __restrict__ a_p, const float* __restrict__ b_p,
    const float* __restrict__ a_r, const float* __restrict__ b_r,
    bf16* __restrict__ xattn)
{
    __shared__ float cosr[15][64];    // cos((rad)*D[j]*c_r), index k=rad+7
    __shared__ float sinr[15][64];
    __shared__ float aphiS[15][16];   // A_phi(az,h), index az+7
    __shared__ float arsS[15][16];    // a_r[(rad)%15][h], index rad+7
    __shared__ float brsS[15][16];
    __shared__ short Vt[32][72];      // V^T per head: Vt[d][j]; 144B rows (16B-aligned)
    __shared__ short Psh[64][72];     // P (bf16, unnormalized) per head

    int b_ = blockIdx.x;              // window index within group
    int bl = b_ >> 6;
    int w  = b_ & 63;
    int wy = w >> 3, wx = w & 7;
    int tid  = threadIdx.x;
    int wave = tid >> 6, lane = tid & 63;

    const float scale = 0.17677669529663687f;   // 1/sqrt(32)
    const float c_az  = 0.09817477042468103f;   // 2*pi/64
    const float c_r   = 0.02454369260617026f;   // 2*pi/256

    // ---- per-window tables (head-independent trig: computed ONCE, not 16x) ----
    for (int t = tid; t < 960; t += 256) {
        int k = t >> 6;               // rad+7 in [0,15)
        int j = t & 63;
        int jy = j >> 3, jx = j & 7;
        float Dj  = Dofs[(size_t)bl * 4096 + (wy * 8 + jy) * 64 + (wx * 8 + jx)];
        float ang = (float)(k - 7) * Dj * c_r;
        cosr[k][j] = __cosf(ang);
        sinr[k][j] = __sinf(ang);
    }
    if (tid < 240) {
        int k = tid >> 4;             // offset+7 in [0,15)
        int h = tid & 15;
        int v = k - 7;
        int ip = v < 0 ? v + 15 : v;  // torch negative-index == mod
        float azf = (float)v * c_az;
        aphiS[k][h] = a_p[ip * 16 + h] * __cosf(azf) + b_p[ip * 16 + h] * __sinf(azf);
        arsS[k][h]  = a_r[ip * 16 + h];
        brsS[k][h]  = b_r[ip * 16 + h];
    }

    int i_blk = wave;                 // this wave's 16 query rows
    int l15 = lane & 15;
    int lq  = lane >> 4;              // 0..3
    int m0  = i_blk * 16 + lq * 4;    // row of reg 0 (D-layout)
    const bf16* qbase = qkv + (size_t)(b_ * 64) * 1536;
    bf16* obase = xattn + (size_t)(b_ * 64) * 512;

    for (int h = 0; h < 16; ++h) {
        __syncthreads();              // prev head's PV done (and tables ready at h=0)
        // ---- stage V^T for this head: thread t -> token t>>2, dims (t&3)*8..+8 ----
        {
            int tok = tid >> 2, dc = (tid & 3) * 8;
            bf16x8 vv = *reinterpret_cast<const bf16x8*>(
                qkv + (size_t)(b_ * 64 + tok) * 1536 + 1024 + h * 32 + dc);
#pragma unroll
            for (int s = 0; s < 8; ++s) Vt[dc + s][tok] = vv[s];
        }
        __syncthreads();              // Vt ready for all waves

        // ---- QK^T: 4 MFMAs (K=32 in one shot), frags straight from global ----
        bf16x8 af = *reinterpret_cast<const bf16x8*>(
            qbase + (size_t)(i_blk * 16 + l15) * 1536 + h * 32 + lq * 8);
        f32x4 Sacc[4] = {};
#pragma unroll
        for (int jb = 0; jb < 4; ++jb) {
            bf16x8 kf = *reinterpret_cast<const bf16x8*>(
                qbase + (size_t)(jb * 16 + l15) * 1536 + 512 + h * 32 + lq * 8);
            Sacc[jb] = __builtin_amdgcn_mfma_f32_16x16x32_bf16(af, kf, Sacc[jb], 0, 0, 0);
        }

        // ---- bias + row softmax in registers ----
        float Sv[4][4];               // [reg][jb]
        float inv[4];
#pragma unroll
        for (int reg = 0; reg < 4; ++reg) {
            int m = m0 + reg;
            int iy = m >> 3, ix = m & 7;
            float rmax = -1e30f;
#pragma unroll
            for (int jb = 0; jb < 4; ++jb) {
                int n = jb * 16 + l15;
                int jy = n >> 3, jx = n & 7;
                int ai = ix - jx + 7;
                int ri = iy - jy + 7;
                float sc = Sacc[jb][reg] * scale + aphiS[ai][h]
                         + arsS[ri][h] * cosr[ri][n] + brsS[ri][h] * sinr[ri][n];
                Sv[reg][jb] = sc;
                rmax = fmaxf(rmax, sc);
            }
#pragma unroll
            for (int off = 1; off <= 8; off <<= 1)
                rmax = fmaxf(rmax, __shfl_xor(rmax, off, 64));
            float rsum = 0.f;
#pragma unroll
            for (int jb = 0; jb < 4; ++jb) {
                float e = __expf(Sv[reg][jb] - rmax);
                Sv[reg][jb] = e;
                rsum += e;
            }
#pragma unroll
            for (int off = 1; off <= 8; off <<= 1)
                rsum += __shfl_xor(rsum, off, 64);
            inv[reg] = 1.0f / rsum;
        }

        // ---- P (bf16, unnormalized) -> LDS; own rows only, no barrier needed ----
#pragma unroll
        for (int reg = 0; reg < 4; ++reg)
#pragma unroll
            for (int jb = 0; jb < 4; ++jb)
                Psh[m0 + reg][jb * 16 + l15] = f2b_s(Sv[reg][jb]);

        // ---- PV: out[m][d] = sum_j P[m][j] * Vt[d][j]; 4 MFMAs ----
        f32x4 o[2] = {};
#pragma unroll
        for (int ks = 0; ks < 2; ++ks) {
            bf16x8 pa = *reinterpret_cast<const bf16x8*>(
                &Psh[i_blk * 16 + l15][ks * 32 + lq * 8]);
#pragma unroll
            for (int nb = 0; nb < 2; ++nb) {
                bf16x8 bv = *reinterpret_cast<const bf16x8*>(
                    &Vt[nb * 16 + l15][ks * 32 + lq * 8]);
                o[nb] = __builtin_amdgcn_mfma_f32_16x16x32_bf16(pa, bv, o[nb], 0, 0, 0);
            }
        }

        // ---- epilogue: normalize by row-sum, store bf16 ----
#pragma unroll
        for (int nb = 0; nb < 2; ++nb) {
            int d = nb * 16 + l15;
#pragma unroll
            for (int reg = 0; reg < 4; ++reg) {
                int m = m0 + reg;
                obase[(size_t)m * 512 + h * 32 + d] = __float2bfloat16(o[nb][reg] * inv[reg]);
            }
        }
    }
}

// ---------------- launch ----------------
extern "C" void kernel_launch(void* const* d_in, const int* in_sizes, int n_in,
                              void* d_out, int out_size, void* d_ws, size_t ws_size,
                              hipStream_t stream)
{
    const float* x      = (const float*)d_in[0];
    const float* D      = (const float*)d_in[1];
    const float* n1g    = (const float*)d_in[2];
    const float* n1b    = (const float*)d_in[3];
    const float* qkv_w  = (const float*)d_in[4];
    const float* qkv_b  = (const float*)d_in[5];
    const float* proj_w = (const float*)d_in[6];
    const float* proj_b = (const float*)d_in[7];
    const float* a_p    = (const float*)d_in[8];
    const float* b_p    = (const float*)d_in[9];
    const float* a_r    = (const float*)d_in[10];
    const float* b_r    = (const float*)d_in[11];
    const float* n2g    = (const float*)d_in[12];
    const float* n2b    = (const float*)d_in[13];
    const float* fc1_w  = (const float*)d_in[14];
    const float* fc1_b  = (const float*)d_in[15];
    const float* fc2_w  = (const float*)d_in[16];
    const float* fc2_b  = (const float*)d_in[17];
    float* out = (float*)d_out;

    // bf16 weights at ws start: 3,145,728 elems = 6,291,456 B
    char* ws = (char*)d_ws;
    short* qkv_wb  = (short*)ws;                 // 1536*512
    short* proj_wb = qkv_wb + 786432;            // 512*512
    short* fc1_wb  = proj_wb + 262144;           // 2048*512
    short* fc2_wb  = fc1_wb + 1048576;           // 512*2048
    char* gws = (char*)(fc2_wb + 1048576);

    // group-local region: 7168 B per row
    int G = 16;
    while (G > 1 && 6291456 + (size_t)G * 4096 * 7168 > ws_size) G >>= 1;
    int NG = 16 / G;
    size_t rowsA = (size_t)G * 4096;

    float* x2   = (float*)gws;                   // rowsA*512 f32
    bf16*  xw   = (bf16*)(gws + rowsA * 2048);   // rowsA*512 bf16 (also xm)
    bf16*  qkvb = xw + rowsA * 512;              // rowsA*1536 bf16
    bf16*  xatt = qkvb + rowsA * 1536;           // rowsA*512 bf16
    bf16*  xm   = xw;
    bf16*  hbuf = qkvb;                          // rowsA*2048 (spans qkv+xatt)

    // convert weights (every call; graph-safe)
    hipLaunchKernelGGL(f2b_kernel, dim3(768),  dim3(256), 0, stream, qkv_w,  qkv_wb,  196608);
    hipLaunchKernelGGL(f2b_kernel, dim3(256),  dim3(256), 0, stream, proj_w, proj_wb,  65536);
    hipLaunchKernelGGL(f2b_kernel, dim3(1024), dim3(256), 0, stream, fc1_w,  fc1_wb,  262144);
    hipLaunchKernelGGL(f2b_kernel, dim3(1024), dim3(256), 0, stream, fc2_w,  fc2_wb,  262144);

    int gy = (int)(rowsA / 128);

    for (int g = 0; g < NG; ++g) {
        size_t r0 = (size_t)g * rowsA;
        // 1. LN1 + window partition -> xw
        hipLaunchKernelGGL(ln_kernel, dim3((int)rowsA), dim3(64), 0, stream,
                           x + r0 * 512, n1g, n1b, xw, 1);
        // 2. QKV GEMM -> qkvb   [rowsA x 1536, K=512]
        hipLaunchKernelGGL(gemm_mfma, dim3(1536 / 128, gy), dim3(256), 0, stream,
                           xw, qkv_wb, qkv_b, 1536, 512, 0, (void*)qkvb, (const float*)nullptr);
        // 3. fused windowed attention (MFMA, one block per window) -> xatt
        hipLaunchKernelGGL(attn_kernel, dim3(G * 64), dim3(256), 0, stream,
                           qkvb, D + r0, a_p, b_p, a_r, b_r, xatt);
        // 4. proj GEMM + window-reverse + residual(x) -> x2 (f32)
        hipLaunchKernelGGL(gemm_mfma, dim3(512 / 128, gy), dim3(256), 0, stream,
                           xatt, proj_wb, proj_b, 512, 512, 1, (void*)x2, x + r0 * 512);
        // 5. LN2 -> xm
        hipLaunchKernelGGL(ln_kernel, dim3((int)rowsA), dim3(64), 0, stream,
                           x2, n2g, n2b, xm, 0);
        // 6. fc1 GEMM + exact GELU -> hbuf  [rowsA x 2048, K=512]
        hipLaunchKernelGGL(gemm_mfma, dim3(2048 / 128, gy), dim3(256), 0, stream,
                           xm, fc1_wb, fc1_b, 2048, 512, 2, (void*)hbuf, (const float*)nullptr);
        // 7. fc2 GEMM + residual(x2) -> out (fp32)  [K=2048]
        hipLaunchKernelGGL(gemm_mfma, dim3(512 / 128, gy), dim3(256), 0, stream,
                           hbuf, fc2_wb, fc2_b, 512, 2048, 3, (void*)(out + r0 * 512), x2);
    }
}

// Round 5
// 1373.730 us; speedup vs baseline: 1.4751x; 1.0322x over previous
//
#include <hip/hip_runtime.h>
#include <hip/hip_bf16.h>
#include <math.h>

typedef __hip_bfloat16 bf16;
using f32x4  = __attribute__((ext_vector_type(4))) float;
using bf16x8 = __attribute__((ext_vector_type(8))) short;

static __device__ __forceinline__ float b2f(bf16 v) { return __bfloat162float(v); }
static __device__ __forceinline__ short f2b_s(float f) {
    bf16 b = __float2bfloat16(f);
    return *reinterpret_cast<short*>(&b);
}

// async 16B/lane global->LDS; lptr must be the wave-uniform chunk base
static __device__ __forceinline__ void gl_lds16(const void* g, void* l) {
    __builtin_amdgcn_global_load_lds(
        (const __attribute__((address_space(1))) unsigned int*)g,
        (__attribute__((address_space(3))) unsigned int*)l, 16, 0, 0);
}

// ---------------- fp32 -> bf16 weight conversion ----------------
__global__ __launch_bounds__(256) void f2b_kernel(const float* __restrict__ in,
                                                  short* __restrict__ out, int n4)
{
    int i = blockIdx.x * 256 + threadIdx.x;
    if (i < n4) {
        float4 f = reinterpret_cast<const float4*>(in)[i];
        short4 s;
        s.x = f2b_s(f.x); s.y = f2b_s(f.y); s.z = f2b_s(f.z); s.w = f2b_s(f.w);
        reinterpret_cast<short4*>(out)[i] = s;
    }
}

// ---------------- LayerNorm (+ optional window partition), f32 in -> bf16 out --
__global__ __launch_bounds__(64) void ln_kernel(
    const float* __restrict__ in, const float* __restrict__ g,
    const float* __restrict__ bta, bf16* __restrict__ out, int windowed)
{
    int lr  = blockIdx.x;
    int tid = threadIdx.x;
    const float* xr = in + (size_t)lr * 512;
    int c0 = tid * 8;
    float4 f0 = *reinterpret_cast<const float4*>(xr + c0);
    float4 f1 = *reinterpret_cast<const float4*>(xr + c0 + 4);
    float v[8] = { f0.x, f0.y, f0.z, f0.w, f1.x, f1.y, f1.z, f1.w };
    float s = 0.f, s2 = 0.f;
#pragma unroll
    for (int k = 0; k < 8; ++k) { s += v[k]; s2 += v[k] * v[k]; }
#pragma unroll
    for (int off = 32; off; off >>= 1) {
        s  += __shfl_xor(s,  off, 64);
        s2 += __shfl_xor(s2, off, 64);
    }
    float mean = s * (1.0f / 512.0f);
    float var  = s2 * (1.0f / 512.0f) - mean * mean;
    float inv  = rsqrtf(var + 1e-5f);
    size_t drow;
    if (windowed) {
        int b_loc = lr >> 12;
        int l  = lr & 4095;
        int gr = l >> 6, gc = l & 63;
        int wy = gr >> 3, iy = gr & 7, wx = gc >> 3, ix = gc & 7;
        drow = (size_t)((b_loc * 64 + wy * 8 + wx) * 64 + iy * 8 + ix);
    } else {
        drow = (size_t)lr;
    }
    bf16* orow = out + drow * 512;
#pragma unroll
    for (int k = 0; k < 8; ++k) {
        int c = c0 + k;
        orow[c] = __float2bfloat16((v[k] - mean) * inv * g[c] + bta[c]);
    }
}

// ---------------- MFMA GEMM: C[M,N] = A[M,K](bf16) @ W[N,K]^T(bf16) ------------
// 128x128 tile, 4 waves (2x2), each wave 4x4 of mfma_f32_16x16x32_bf16, BK=32.
// T4 counted-vmcnt pipeline, depth 2: 3 statically-named LDS buffer pairs.
// While computing step s, stages s+1 and s+2 are in flight (8 loads/wave);
// before compute: vmcnt(8) (NEVER 0 in main loop) + raw s_barrier. Loads ride
// through barriers and drain under two steps of MFMA work.
// End-barrier per step keeps overwrite of buf[(s+2)%3] race-free.
// T1 XCD-aware bijective block swizzle kept (FETCH verified near-ideal R4).
// modes: 0 = +bias -> bf16 dst
//        1 = +bias + residual(res f32, window-reversed LOCAL idx) -> f32 dst
//        2 = +bias, exact GELU -> bf16 dst
//        3 = +bias + residual(res f32, same local idx) -> f32 dst (final output)
__global__ __launch_bounds__(256) void gemm_mfma(
    const bf16* __restrict__ A, const short* __restrict__ W,
    const float* __restrict__ bias, int N, int K, int mode,
    void* __restrict__ dstv, const float* __restrict__ res)
{
    __shared__ short As0[128 * 32];   // 8 KB each; 48 KB total -> 3 blocks/CU
    __shared__ short Bs0[128 * 32];
    __shared__ short As1[128 * 32];
    __shared__ short Bs1[128 * 32];
    __shared__ short As2[128 * 32];
    __shared__ short Bs2[128 * 32];

    int tid  = threadIdx.x;
    int wave = tid >> 6, lane = tid & 63;
    int waveM = wave >> 1, waveN = wave & 1;

    // T1: XCD-aware bijective swizzle; each XCD owns a contiguous chunk of
    // linear block ids, x (column blocks) walking fastest -> A-panel L2 reuse.
    int nx  = gridDim.x;
    int nwg = nx * gridDim.y;
    int lid = blockIdx.y * nx + blockIdx.x;
    int nid = lid;
    if ((nwg & 7) == 0) nid = (lid & 7) * (nwg >> 3) + (lid >> 3);
    int mBase = (nid / nx) * 128;
    int nBase = (nid % nx) * 128;

    f32x4 acc[4][4] = {};

    // staging: wave w covers rows w*32 .. w*32+31 (two 16-row instructions each)
    int rr   = wave * 32 + (lane >> 2);          // rows w*32 .. w*32+15
    int segE = (lane & 3) * 8;                   // 16B segment within 64B row
    const bf16*  Ag = A + (size_t)(mBase + rr) * K + segE;
    const short* Bg = W + (size_t)(nBase + rr) * K + segE;
    size_t rs16 = (size_t)16 * K;                // 16-row stride in elements

    int mf = waveM * 64 + (lane & 15);           // fragment row (A)
    int nf = waveN * 64 + (lane & 15);           // fragment row (B)
    int kq = (lane >> 4) * 8;                    // quad k-offset

    auto stage = [&](int kb, short* Ad, short* Bd) {
        gl_lds16(Ag + kb,        Ad + wave * 1024);
        gl_lds16(Ag + kb + rs16, Ad + wave * 1024 + 512);
        gl_lds16(Bg + kb,        Bd + wave * 1024);
        gl_lds16(Bg + kb + rs16, Bd + wave * 1024 + 512);
    };
    auto compute = [&](const short* As_, const short* Bs_) {
        bf16x8 af[4], bfv[4];
#pragma unroll
        for (int i = 0; i < 4; ++i)
            af[i] = *reinterpret_cast<const bf16x8*>(&As_[(mf + i * 16) * 32 + kq]);
#pragma unroll
        for (int j = 0; j < 4; ++j)
            bfv[j] = *reinterpret_cast<const bf16x8*>(&Bs_[(nf + j * 16) * 32 + kq]);
#pragma unroll
        for (int i = 0; i < 4; ++i)
#pragma unroll
            for (int j = 0; j < 4; ++j)
                acc[i][j] = __builtin_amdgcn_mfma_f32_16x16x32_bf16(af[i], bfv[j], acc[i][j], 0, 0, 0);
    };

    int nsteps = K >> 5;                         // 16 (K=512) or 64 (K=2048)

    // ---- prologue: stage steps 0 and 1 ----
    stage(0,  As0, Bs0);
    stage(32, As1, Bs1);

    // Per slot S: optionally stage S+2 (depth-2), wait ONLY for S's own 4 loads
    // (vmcnt(8): the 8 younger loads stay in flight), barrier, compute, barrier.
#define SLOT(S, CA, CB, SA, SB)                                                  \
    if ((S) < nsteps) {                                                          \
        if ((S) + 2 < nsteps) stage(((S) + 2) << 5, SA, SB);                     \
        if ((S) + 2 < nsteps)                                                    \
            asm volatile("s_waitcnt vmcnt(8)" ::: "memory");                     \
        else if ((S) + 1 < nsteps)                                               \
            asm volatile("s_waitcnt vmcnt(4)" ::: "memory");                     \
        else                                                                     \
            asm volatile("s_waitcnt vmcnt(0)" ::: "memory");                     \
        __builtin_amdgcn_s_barrier();                                            \
        __builtin_amdgcn_sched_barrier(0);                                       \
        compute(CA, CB);                                                         \
        __builtin_amdgcn_sched_barrier(0);                                       \
        __builtin_amdgcn_s_barrier();                                            \
    }

    for (int s = 0; s < nsteps; s += 3) {
        SLOT(s,     As0, Bs0, As2, Bs2);
        SLOT(s + 1, As1, Bs1, As0, Bs0);
        SLOT(s + 2, As2, Bs2, As1, Bs1);
    }
#undef SLOT

    // epilogue: C/D layout col=lane&15, row=(lane>>4)*4+reg
    int rq = (lane >> 4) * 4;
#pragma unroll
    for (int j = 0; j < 4; ++j) {
        int n = nBase + waveN * 64 + j * 16 + (lane & 15);
        float bn = bias[n];
#pragma unroll
        for (int i = 0; i < 4; ++i) {
#pragma unroll
            for (int reg = 0; reg < 4; ++reg) {
                int m = mBase + waveM * 64 + i * 16 + rq + reg;
                float v = acc[i][j][reg] + bn;
                if (mode == 0) {
                    ((bf16*)dstv)[(size_t)m * N + n] = __float2bfloat16(v);
                } else if (mode == 1) {
                    int b_loc = m >> 12, w = (m >> 6) & 63, tk = m & 63;
                    int wy = w >> 3, wx = w & 7, iy = tk >> 3, ix = tk & 7;
                    int l = ((wy << 3) + iy) * 64 + (wx << 3) + ix;
                    size_t idx = ((size_t)(b_loc * 4096 + l)) * 512 + n;
                    ((float*)dstv)[idx] = v + res[idx];
                } else if (mode == 2) {
                    float gl = 0.5f * v * (1.0f + erff(v * 0.70710678118654752f));
                    ((bf16*)dstv)[(size_t)m * N + n] = __float2bfloat16(gl);
                } else {
                    size_t idx = (size_t)m * N + n;
                    ((float*)dstv)[idx] = v + res[idx];
                }
            }
        }
    }
}

// ---------------- Fused windowed attention, MFMA version ----------------
// One block (256 thr = 4 waves) per window; 16 heads looped inside.
__global__ __launch_bounds__(256) void attn_kernel(
    const bf16* __restrict__ qkv, const float* __restrict__ Dofs,
    const float* __restrict__ a_p, const float* __restrict__ b_p,
    const float* __restrict__ a_r, const float* __restrict__ b_r,
    bf16* __restrict__ xattn)
{
    __shared__ float cosr[15][64];    // cos((rad)*D[j]*c_r), index k=rad+7
    __shared__ float sinr[15][64];
    __shared__ float aphiS[15][16];   // A_phi(az,h), index az+7
    __shared__ float arsS[15][16];    // a_r[(rad)%15][h], index rad+7
    __shared__ float brsS[15][16];
    __shared__ short Vt[32][72];      // V^T per head: Vt[d][j]; 144B rows (16B-aligned)
    __shared__ short Psh[64][72];     // P (bf16, unnormalized) per head

    int b_ = blockIdx.x;              // window index within group
    int bl = b_ >> 6;
    int w  = b_ & 63;
    int wy = w >> 3, wx = w & 7;
    int tid  = threadIdx.x;
    int wave = tid >> 6, lane = tid & 63;

    const float scale = 0.17677669529663687f;   // 1/sqrt(32)
    const float c_az  = 0.09817477042468103f;   // 2*pi/64
    const float c_r   = 0.02454369260617026f;   // 2*pi/256

    // ---- per-window tables (head-independent trig: computed ONCE, not 16x) ----
    for (int t = tid; t < 960; t += 256) {
        int k = t >> 6;               // rad+7 in [0,15)
        int j = t & 63;
        int jy = j >> 3, jx = j & 7;
        float Dj  = Dofs[(size_t)bl * 4096 + (wy * 8 + jy) * 64 + (wx * 8 + jx)];
        float ang = (float)(k - 7) * Dj * c_r;
        cosr[k][j] = __cosf(ang);
        sinr[k][j] = __sinf(ang);
    }
    if (tid < 240) {
        int k = tid >> 4;             // offset+7 in [0,15)
        int h = tid & 15;
        int v = k - 7;
        int ip = v < 0 ? v + 15 : v;  // torch negative-index == mod
        float azf = (float)v * c_az;
        aphiS[k][h] = a_p[ip * 16 + h] * __cosf(azf) + b_p[ip * 16 + h] * __sinf(azf);
        arsS[k][h]  = a_r[ip * 16 + h];
        brsS[k][h]  = b_r[ip * 16 + h];
    }

    int i_blk = wave;                 // this wave's 16 query rows
    int l15 = lane & 15;
    int lq  = lane >> 4;              // 0..3
    int m0  = i_blk * 16 + lq * 4;    // row of reg 0 (D-layout)
    const bf16* qbase = qkv + (size_t)(b_ * 64) * 1536;
    bf16* obase = xattn + (size_t)(b_ * 64) * 512;

    for (int h = 0; h < 16; ++h) {
        __syncthreads();              // prev head's PV done (and tables ready at h=0)
        // ---- stage V^T for this head: thread t -> token t>>2, dims (t&3)*8..+8 ----
        {
            int tok = tid >> 2, dc = (tid & 3) * 8;
            bf16x8 vv = *reinterpret_cast<const bf16x8*>(
                qkv + (size_t)(b_ * 64 + tok) * 1536 + 1024 + h * 32 + dc);
#pragma unroll
            for (int s = 0; s < 8; ++s) Vt[dc + s][tok] = vv[s];
        }
        __syncthreads();              // Vt ready for all waves

        // ---- QK^T: 4 MFMAs (K=32 in one shot), frags straight from global ----
        bf16x8 af = *reinterpret_cast<const bf16x8*>(
            qbase + (size_t)(i_blk * 16 + l15) * 1536 + h * 32 + lq * 8);
        f32x4 Sacc[4] = {};
#pragma unroll
        for (int jb = 0; jb < 4; ++jb) {
            bf16x8 kf = *reinterpret_cast<const bf16x8*>(
                qbase + (size_t)(jb * 16 + l15) * 1536 + 512 + h * 32 + lq * 8);
            Sacc[jb] = __builtin_amdgcn_mfma_f32_16x16x32_bf16(af, kf, Sacc[jb], 0, 0, 0);
        }

        // ---- bias + row softmax in registers ----
        float Sv[4][4];               // [reg][jb]
        float inv[4];
#pragma unroll
        for (int reg = 0; reg < 4; ++reg) {
            int m = m0 + reg;
            int iy = m >> 3, ix = m & 7;
            float rmax = -1e30f;
#pragma unroll
            for (int jb = 0; jb < 4; ++jb) {
                int n = jb * 16 + l15;
                int jy = n >> 3, jx = n & 7;
                int ai = ix - jx + 7;
                int ri = iy - jy + 7;
                float sc = Sacc[jb][reg] * scale + aphiS[ai][h]
                         + arsS[ri][h] * cosr[ri][n] + brsS[ri][h] * sinr[ri][n];
                Sv[reg][jb] = sc;
                rmax = fmaxf(rmax, sc);
            }
#pragma unroll
            for (int off = 1; off <= 8; off <<= 1)
                rmax = fmaxf(rmax, __shfl_xor(rmax, off, 64));
            float rsum = 0.f;
#pragma unroll
            for (int jb = 0; jb < 4; ++jb) {
                float e = __expf(Sv[reg][jb] - rmax);
                Sv[reg][jb] = e;
                rsum += e;
            }
#pragma unroll
            for (int off = 1; off <= 8; off <<= 1)
                rsum += __shfl_xor(rsum, off, 64);
            inv[reg] = 1.0f / rsum;
        }

        // ---- P (bf16, unnormalized) -> LDS; own rows only, no barrier needed ----
#pragma unroll
        for (int reg = 0; reg < 4; ++reg)
#pragma unroll
            for (int jb = 0; jb < 4; ++jb)
                Psh[m0 + reg][jb * 16 + l15] = f2b_s(Sv[reg][jb]);

        // ---- PV: out[m][d] = sum_j P[m][j] * Vt[d][j]; 4 MFMAs ----
        f32x4 o[2] = {};
#pragma unroll
        for (int ks = 0; ks < 2; ++ks) {
            bf16x8 pa = *reinterpret_cast<const bf16x8*>(
                &Psh[i_blk * 16 + l15][ks * 32 + lq * 8]);
#pragma unroll
            for (int nb = 0; nb < 2; ++nb) {
                bf16x8 bv = *reinterpret_cast<const bf16x8*>(
                    &Vt[nb * 16 + l15][ks * 32 + lq * 8]);
                o[nb] = __builtin_amdgcn_mfma_f32_16x16x32_bf16(pa, bv, o[nb], 0, 0, 0);
            }
        }

        // ---- epilogue: normalize by row-sum, store bf16 ----
#pragma unroll
        for (int nb = 0; nb < 2; ++nb) {
            int d = nb * 16 + l15;
#pragma unroll
            for (int reg = 0; reg < 4; ++reg) {
                int m = m0 + reg;
                obase[(size_t)m * 512 + h * 32 + d] = __float2bfloat16(o[nb][reg] * inv[reg]);
            }
        }
    }
}

// ---------------- launch ----------------
extern "C" void kernel_launch(void* const* d_in, const int* in_sizes, int n_in,
                              void* d_out, int out_size, void* d_ws, size_t ws_size,
                              hipStream_t stream)
{
    const float* x      = (const float*)d_in[0];
    const float* D      = (const float*)d_in[1];
    const float* n1g    = (const float*)d_in[2];
    const float* n1b    = (const float*)d_in[3];
    const float* qkv_w  = (const float*)d_in[4];
    const float* qkv_b  = (const float*)d_in[5];
    const float* proj_w = (const float*)d_in[6];
    const float* proj_b = (const float*)d_in[7];
    const float* a_p    = (const float*)d_in[8];
    const float* b_p    = (const float*)d_in[9];
    const float* a_r    = (const float*)d_in[10];
    const float* b_r    = (const float*)d_in[11];
    const float* n2g    = (const float*)d_in[12];
    const float* n2b    = (const float*)d_in[13];
    const float* fc1_w  = (const float*)d_in[14];
    const float* fc1_b  = (const float*)d_in[15];
    const float* fc2_w  = (const float*)d_in[16];
    const float* fc2_b  = (const float*)d_in[17];
    float* out = (float*)d_out;

    // bf16 weights at ws start: 3,145,728 elems = 6,291,456 B
    char* ws = (char*)d_ws;
    short* qkv_wb  = (short*)ws;                 // 1536*512
    short* proj_wb = qkv_wb + 786432;            // 512*512
    short* fc1_wb  = proj_wb + 262144;           // 2048*512
    short* fc2_wb  = fc1_wb + 1048576;           // 512*2048
    char* gws = (char*)(fc2_wb + 1048576);

    // group-local region: 7168 B per row
    int G = 16;
    while (G > 1 && 6291456 + (size_t)G * 4096 * 7168 > ws_size) G >>= 1;
    int NG = 16 / G;
    size_t rowsA = (size_t)G * 4096;

    float* x2   = (float*)gws;                   // rowsA*512 f32
    bf16*  xw   = (bf16*)(gws + rowsA * 2048);   // rowsA*512 bf16 (also xm)
    bf16*  qkvb = xw + rowsA * 512;              // rowsA*1536 bf16
    bf16*  xatt = qkvb + rowsA * 1536;           // rowsA*512 bf16
    bf16*  xm   = xw;
    bf16*  hbuf = qkvb;                          // rowsA*2048 (spans qkv+xatt)

    // convert weights (every call; graph-safe)
    hipLaunchKernelGGL(f2b_kernel, dim3(768),  dim3(256), 0, stream, qkv_w,  qkv_wb,  196608);
    hipLaunchKernelGGL(f2b_kernel, dim3(256),  dim3(256), 0, stream, proj_w, proj_wb,  65536);
    hipLaunchKernelGGL(f2b_kernel, dim3(1024), dim3(256), 0, stream, fc1_w,  fc1_wb,  262144);
    hipLaunchKernelGGL(f2b_kernel, dim3(1024), dim3(256), 0, stream, fc2_w,  fc2_wb,  262144);

    int gy = (int)(rowsA / 128);

    for (int g = 0; g < NG; ++g) {
        size_t r0 = (size_t)g * rowsA;
        // 1. LN1 + window partition -> xw
        hipLaunchKernelGGL(ln_kernel, dim3((int)rowsA), dim3(64), 0, stream,
                           x + r0 * 512, n1g, n1b, xw, 1);
        // 2. QKV GEMM -> qkvb   [rowsA x 1536, K=512]
        hipLaunchKernelGGL(gemm_mfma, dim3(1536 / 128, gy), dim3(256), 0, stream,
                           xw, qkv_wb, qkv_b, 1536, 512, 0, (void*)qkvb, (const float*)nullptr);
        // 3. fused windowed attention (MFMA, one block per window) -> xatt
        hipLaunchKernelGGL(attn_kernel, dim3(G * 1024 / 16), dim3(256), 0, stream,
                           qkvb, D + r0, a_p, b_p, a_r, b_r, xatt);
        // 4. proj GEMM + window-reverse + residual(x) -> x2 (f32)
        hipLaunchKernelGGL(gemm_mfma, dim3(512 / 128, gy), dim3(256), 0, stream,
                           xatt, proj_wb, proj_b, 512, 512, 1, (void*)x2, x + r0 * 512);
        // 5. LN2 -> xm
        hipLaunchKernelGGL(ln_kernel, dim3((int)rowsA), dim3(64), 0, stream,
                           x2, n2g, n2b, xm, 0);
        // 6. fc1 GEMM + exact GELU -> hbuf  [rowsA x 2048, K=512]
        hipLaunchKernelGGL(gemm_mfma, dim3(2048 / 128, gy), dim3(256), 0, stream,
                           xm, fc1_wb, fc1_b, 2048, 512, 2, (void*)hbuf, (const float*)nullptr);
        // 7. fc2 GEMM + residual(x2) -> out (fp32)  [K=2048]
        hipLaunchKernelGGL(gemm_mfma, dim3(512 / 128, gy), dim3(256), 0, stream,
                           hbuf, fc2_wb, fc2_b, 512, 2048, 3, (void*)(out + r0 * 512), x2);
    }
}